// Round 2
// baseline (5714.272 us; speedup 1.0000x reference)
//
#include <hip/hip_runtime.h>
#include <hip/hip_bf16.h>
#include <math.h>

#define Bn 4
#define Sn 6
#define Cin 8
#define Hh 96
#define Ww 96
#define HW (Hh*Ww)          // 9216
#define Chn 64
#define Ln 13
#define LCh (Ln*Chn)        // 832
#define OC3 (3*Chn)         // 192
#define LEAK 0.2f

typedef __hip_bfloat16 bf16;

__device__ __forceinline__ float b2f(bf16 v){ return __bfloat162float(v); }

// ---------------- i2h: 3x3 conv Cin(8) -> 192, one timestep ----------------
__global__ void k_i2h(const float* __restrict__ x, const float* __restrict__ w,
                      const float* __restrict__ bias, bf16* __restrict__ out, int t)
{
    int pix = blockIdx.x*256 + threadIdx.x;          // 36*256 = 9216
    int oc = blockIdx.y, b = blockIdx.z;
    int y = pix / Ww, xc = pix % Ww;
    float acc = bias[oc];
    const float* xb = x + ((size_t)(b*Sn + t)*Cin)*HW;
    const float* wp = w + (size_t)oc*Cin*9;
    for (int ic=0; ic<Cin; ++ic){
        for (int ky=0; ky<3; ++ky){
            int yy = y + ky - 1; if (yy<0 || yy>=Hh) continue;
            for (int kx=0; kx<3; ++kx){
                int xx = xc + kx - 1; if (xx<0 || xx>=Ww) continue;
                acc += wp[(ic*3+ky)*3+kx] * xb[(size_t)ic*HW + yy*Ww + xx];
            }
        }
    }
    out[((size_t)(b*OC3+oc))*HW + pix] = __float2bfloat16(acc);
}

// ---------------- conv1: 3x3 conv concat[x(8), h(64)] -> 32, LeakyReLU -----
__global__ void k_conv1(const float* __restrict__ x, const float* __restrict__ h,
                        const float* __restrict__ w, const float* __restrict__ bias,
                        bf16* __restrict__ f, int t)
{
    int pix = blockIdx.x*256 + threadIdx.x;
    int oc = blockIdx.y, b = blockIdx.z;
    int y = pix / Ww, xc = pix % Ww;
    float acc = bias[oc];
    const float* xb = x + ((size_t)(b*Sn + t)*Cin)*HW;
    const float* hb = h + (size_t)b*Chn*HW;
    const float* wp = w + (size_t)oc*(Cin+Chn)*9;
    // x part (channels 0..7 of the concat)
    for (int ic=0; ic<Cin; ++ic){
        for (int ky=0; ky<3; ++ky){
            int yy = y + ky - 1; if (yy<0 || yy>=Hh) continue;
            for (int kx=0; kx<3; ++kx){
                int xx = xc + kx - 1; if (xx<0 || xx>=Ww) continue;
                acc += wp[(ic*3+ky)*3+kx] * xb[(size_t)ic*HW + yy*Ww + xx];
            }
        }
    }
    // h part (channels 8..71)
    for (int c=0; c<Chn; ++c){
        const float* wpc = wp + (size_t)(Cin+c)*9;
        const float* hc = hb + (size_t)c*HW;
        for (int ky=0; ky<3; ++ky){
            int yy = y + ky - 1; if (yy<0 || yy>=Hh) continue;
            for (int kx=0; kx<3; ++kx){
                int xx = xc + kx - 1; if (xx<0 || xx>=Ww) continue;
                acc += wpc[ky*3+kx] * hc[yy*Ww + xx];
            }
        }
    }
    f[((size_t)(b*32+oc))*HW + pix] = __float2bfloat16((acc >= 0.f) ? acc : LEAK*acc);
}

// ---------------- conv2: 3x3 conv 32 -> 26 (flows) -------------------------
__global__ void k_conv2(const bf16* __restrict__ f, const float* __restrict__ w,
                        const float* __restrict__ bias, float* __restrict__ flows)
{
    int pix = blockIdx.x*256 + threadIdx.x;
    int oc = blockIdx.y, b = blockIdx.z;
    int y = pix / Ww, xc = pix % Ww;
    float acc = bias[oc];
    const bf16* fb = f + (size_t)b*32*HW;
    const float* wp = w + (size_t)oc*32*9;
    for (int ic=0; ic<32; ++ic){
        const bf16* fc = fb + (size_t)ic*HW;
        for (int ky=0; ky<3; ++ky){
            int yy = y + ky - 1; if (yy<0 || yy>=Hh) continue;
            for (int kx=0; kx<3; ++kx){
                int xx = xc + kx - 1; if (xx<0 || xx>=Ww) continue;
                acc += wp[(ic*3+ky)*3+kx] * b2f(fc[yy*Ww + xx]);
            }
        }
    }
    flows[((size_t)(b*2*Ln+oc))*HW + pix] = acc;
}

// ---------------- warp: bilinear sample h by -flow, zero pad (one batch) ---
__global__ void k_warp(const float* __restrict__ flows, const float* __restrict__ h,
                       bf16* __restrict__ warped, int b)
{
    int pix = blockIdx.x*256 + threadIdx.x;
    int l = blockIdx.y;
    int y = pix / Ww, xc = pix % Ww;
    float fx = flows[((size_t)(b*2*Ln + 2*l  ))*HW + pix];
    float fy = flows[((size_t)(b*2*Ln + 2*l+1))*HW + pix];
    float vx = (float)xc - fx;
    float vy = (float)y  - fy;
    // align_corners=False unnormalize composed: ix = vx*W/(W-1) - 0.5
    float ix = vx * (96.0f/95.0f) - 0.5f;
    float iy = vy * (96.0f/95.0f) - 0.5f;
    float x0f = floorf(ix), y0f = floorf(iy);
    float wx1 = ix - x0f,  wy1 = iy - y0f;
    float wx0 = 1.f - wx1, wy0 = 1.f - wy1;
    float x1f = x0f + 1.f, y1f = y0f + 1.f;
    float vx0 = (x0f >= 0.f && x0f <= 95.f) ? 1.f : 0.f;
    float vx1 = (x1f >= 0.f && x1f <= 95.f) ? 1.f : 0.f;
    float vy0 = (y0f >= 0.f && y0f <= 95.f) ? 1.f : 0.f;
    float vy1 = (y1f >= 0.f && y1f <= 95.f) ? 1.f : 0.f;
    int xi0 = (int)fminf(fmaxf(x0f, 0.f), 95.f);
    int xi1 = (int)fminf(fmaxf(x1f, 0.f), 95.f);
    int yi0 = (int)fminf(fmaxf(y0f, 0.f), 95.f);
    int yi1 = (int)fminf(fmaxf(y1f, 0.f), 95.f);
    float w00 = wx0*wy0*vx0*vy0, w10 = wx1*wy0*vx1*vy0;
    float w01 = wx0*wy1*vx0*vy1, w11 = wx1*wy1*vx1*vy1;
    int o00 = yi0*Ww + xi0, o10 = yi0*Ww + xi1;
    int o01 = yi1*Ww + xi0, o11 = yi1*Ww + xi1;
    const float* hb = h + (size_t)b*Chn*HW;
    bf16* wb = warped + ((size_t)l*Chn)*HW + pix;   // per-batch buffer
    for (int c=0; c<Chn; ++c){
        const float* hc = hb + (size_t)c*HW;
        float v = hc[o00]*w00 + hc[o10]*w10 + hc[o01]*w01 + hc[o11]*w11;
        wb[(size_t)c*HW] = __float2bfloat16(v);
    }
}

// ---------------- h2h: 1x1 conv 832 -> 192 (8 oc per block, one batch) -----
__global__ void k_h2h(const bf16* __restrict__ warped, const float* __restrict__ rw,
                      const float* __restrict__ rb, bf16* __restrict__ h2h, int b)
{
    __shared__ float wsm[8*LCh];                     // 26.6 KB
    int tid = threadIdx.x;
    int ocb = blockIdx.y;                            // 0..23
    for (int i = tid; i < 8*LCh; i += 256)
        wsm[i] = rw[(size_t)(ocb*8 + i/LCh)*LCh + (i % LCh)];
    __syncthreads();
    int pix = blockIdx.x*256 + tid;
    float acc[8];
    #pragma unroll
    for (int j=0; j<8; ++j) acc[j] = rb[ocb*8+j];
    const bf16* wp = warped + pix;                   // per-batch buffer
    for (int ic=0; ic<LCh; ++ic){
        float v = b2f(wp[(size_t)ic*HW]);
        #pragma unroll
        for (int j=0; j<8; ++j) acc[j] += wsm[j*LCh+ic] * v;
    }
    #pragma unroll
    for (int j=0; j<8; ++j)
        h2h[((size_t)(b*OC3) + ocb*8 + j)*HW + pix] = __float2bfloat16(acc[j]);
}

// ---------------- gates: GRU update, write nh to h and to out --------------
__global__ void k_gates(const bf16* __restrict__ i2h, const bf16* __restrict__ h2h,
                        float* __restrict__ h, float* __restrict__ out, int t)
{
    int pix = blockIdx.x*256 + threadIdx.x;
    int cc = blockIdx.y, b = blockIdx.z;
    size_t base = (size_t)b*OC3*HW + pix;
    float i1 = b2f(i2h[base + (size_t)cc*HW]);
    float i2v= b2f(i2h[base + (size_t)(cc+ 64)*HW]);
    float i3 = b2f(i2h[base + (size_t)(cc+128)*HW]);
    float h1 = b2f(h2h[base + (size_t)cc*HW]);
    float h2v= b2f(h2h[base + (size_t)(cc+ 64)*HW]);
    float h3 = b2f(h2h[base + (size_t)(cc+128)*HW]);
    size_t hidx = ((size_t)b*Chn + cc)*HW + pix;
    float hv = h[hidx];
    float r = 1.f/(1.f + expf(-(i1 + h1)));
    float u = 1.f/(1.f + expf(-(i2v + h2v)));
    float mp = i3 + r*h3;
    float m = (mp >= 0.f) ? mp : LEAK*mp;
    float nh = u*hv + (1.f - u)*m;
    h[hidx] = nh;
    out[(((size_t)(b*Sn+t)*Chn) + cc)*HW + pix] = nh;
}

// ---------------- init h from states; final copy h -> last_h ---------------
__global__ void k_init_h(const float* __restrict__ states, float* __restrict__ h)
{
    int i = blockIdx.x*256 + threadIdx.x;
    if (i < Bn*Chn*HW) h[i] = states[i];
}

__global__ void k_last(const float* __restrict__ h, float* __restrict__ out)
{
    int i = blockIdx.x*256 + threadIdx.x;
    if (i < Bn*Chn*HW) out[(size_t)Bn*Sn*Chn*HW + i] = h[i];
}

extern "C" void kernel_launch(void* const* d_in, const int* in_sizes, int n_in,
                              void* d_out, int out_size, void* d_ws, size_t ws_size,
                              hipStream_t stream) {
    const float* inputs = (const float*)d_in[0];
    const float* states = (const float*)d_in[1];
    const float* fw1    = (const float*)d_in[2];
    const float* fb1    = (const float*)d_in[3];
    const float* fw2    = (const float*)d_in[4];
    const float* fb2    = (const float*)d_in[5];
    const float* i2h_w  = (const float*)d_in[6];
    const float* i2h_b  = (const float*)d_in[7];
    const float* ret_w  = (const float*)d_in[8];
    const float* ret_b  = (const float*)d_in[9];
    float* out = (float*)d_out;

    // workspace layout (bytes), total 59,277,312 (~59.3 MB)
    char* ws = (char*)d_ws;
    float* h_ws     = (float*)(ws);                  //  9,437,184  (B*64*HW f32)
    bf16*  i2h_ws   = (bf16*) (ws +  9437184);       // 14,155,776  (B*192*HW bf16)
    bf16*  f_ws     = (bf16*) (ws + 23592960);       //  2,359,296  (B*32*HW bf16)
    float* flows_ws = (float*)(ws + 25952256);       //  3,833,856  (B*26*HW f32)
    bf16*  h2h_ws   = (bf16*) (ws + 29786112);       // 14,155,776  (B*192*HW bf16)
    bf16*  warped_ws= (bf16*) (ws + 43941888);       // 15,335,424  (832*HW bf16, ONE batch)

    k_init_h<<<dim3((Bn*Chn*HW+255)/256), 256, 0, stream>>>(states, h_ws);

    for (int t = 0; t < Sn; ++t) {
        k_i2h  <<<dim3(36, OC3, Bn), 256, 0, stream>>>(inputs, i2h_w, i2h_b, i2h_ws, t);
        k_conv1<<<dim3(36,  32, Bn), 256, 0, stream>>>(inputs, h_ws, fw1, fb1, f_ws, t);
        k_conv2<<<dim3(36, 2*Ln, Bn),256, 0, stream>>>(f_ws, fw2, fb2, flows_ws);
        for (int b = 0; b < Bn; ++b) {
            k_warp <<<dim3(36, Ln), 256, 0, stream>>>(flows_ws, h_ws, warped_ws, b);
            k_h2h  <<<dim3(36, 24), 256, 0, stream>>>(warped_ws, ret_w, ret_b, h2h_ws, b);
        }
        k_gates<<<dim3(36, Chn, Bn), 256, 0, stream>>>(i2h_ws, h2h_ws, h_ws, out, t);
    }
    k_last<<<dim3((Bn*Chn*HW+255)/256), 256, 0, stream>>>(h_ws, out);
}

// Round 3
// 3024.384 us; speedup vs baseline: 1.8894x; 1.8894x over previous
//
#include <hip/hip_runtime.h>
#include <hip/hip_bf16.h>
#include <math.h>

#define Bn 4
#define Sn 6
#define Cin 8
#define Hh 96
#define Ww 96
#define HW (Hh*Ww)          // 9216
#define Chn 64
#define Ln 13
#define LCh (Ln*Chn)        // 832
#define OC3 (3*Chn)         // 192
#define LEAK 0.2f

typedef __hip_bfloat16 bf16;
typedef __attribute__((ext_vector_type(8))) short short8v;  // 8 bf16 (4 VGPRs)
typedef __attribute__((ext_vector_type(4))) float f32x4;

__device__ __forceinline__ float b2f(bf16 v){ return __bfloat162float(v); }
__device__ __forceinline__ bf16  f2b(float v){ return __float2bfloat16(v); }

// ---------------- convert ret_w fp32 -> bf16 (once) ------------------------
__global__ void k_wcvt(const float* __restrict__ w, bf16* __restrict__ wb, int n){
    int i = blockIdx.x*256 + threadIdx.x;
    if (i < n) wb[i] = f2b(w[i]);
}

// ---------------- init h (bf16 CHW) from states ----------------------------
__global__ void k_init(const float* __restrict__ s, bf16* __restrict__ h){
    int i = blockIdx.x*256 + threadIdx.x;
    if (i < Bn*Chn*HW) h[i] = f2b(s[i]);
}

// ---------------- transpose h CHW -> HWC (bf16), LDS-tiled -----------------
__global__ void k_tr(const bf16* __restrict__ chw, bf16* __restrict__ hwc){
    __shared__ unsigned short t[64][65];
    int b = blockIdx.y;
    int pix0 = blockIdx.x*64;
    int tid = threadIdx.x;
    const unsigned short* src = (const unsigned short*)chw;
    unsigned short* dst = (unsigned short*)hwc;
    #pragma unroll
    for (int it=0; it<16; ++it){
        int idx = it*256 + tid;          // 0..4095
        int c = idx>>6, p = idx&63;
        t[c][p] = src[((size_t)b*Chn + c)*HW + pix0 + p];
    }
    __syncthreads();
    #pragma unroll
    for (int it=0; it<16; ++it){
        int idx = it*256 + tid;
        int p = idx>>6, c = idx&63;
        dst[((size_t)b*HW + pix0 + p)*Chn + c] = t[c][p];
    }
}

// ---------------- i2h: 3x3 conv 8 -> 192, 16 oc per block ------------------
__global__ void k_i2h(const float* __restrict__ x, const float* __restrict__ w,
                      const float* __restrict__ bias, bf16* __restrict__ out, int t)
{
    __shared__ float wl[Cin*9*16];                   // 4608 B, [(ic*9+tap)*16 + j]
    int tid = threadIdx.x;
    int oc0 = blockIdx.y*16, b = blockIdx.z;
    for (int i = tid; i < Cin*9*16; i += 256){
        int j = i & 15, kt = i >> 4;
        wl[i] = w[(size_t)(oc0 + j)*(Cin*9) + kt];
    }
    __syncthreads();
    int pix = blockIdx.x*256 + tid;
    int y = pix / Ww, xc = pix % Ww;
    float acc[16];
    #pragma unroll
    for (int j=0;j<16;++j) acc[j] = bias[oc0+j];
    const float* xb = x + ((size_t)(b*Sn + t)*Cin)*HW;
    for (int ic=0; ic<Cin; ++ic){
        float tv[9];
        #pragma unroll
        for (int ky=0; ky<3; ++ky){
            int yy = y + ky - 1;
            #pragma unroll
            for (int kx=0; kx<3; ++kx){
                int xx = xc + kx - 1;
                bool ok = (yy>=0 && yy<Hh && xx>=0 && xx<Ww);
                tv[ky*3+kx] = ok ? xb[(size_t)ic*HW + yy*Ww + xx] : 0.f;
            }
        }
        #pragma unroll
        for (int tp=0; tp<9; ++tp){
            const float4* wp4 = (const float4*)&wl[(ic*9+tp)*16];
            float tvv = tv[tp];
            #pragma unroll
            for (int q=0;q<4;++q){
                float4 wv = wp4[q];
                acc[q*4+0] += tvv*wv.x; acc[q*4+1] += tvv*wv.y;
                acc[q*4+2] += tvv*wv.z; acc[q*4+3] += tvv*wv.w;
            }
        }
    }
    #pragma unroll
    for (int j=0;j<16;++j)
        out[((size_t)(b*OC3) + oc0 + j)*HW + pix] = f2b(acc[j]);
}

// ---------------- conv1: 3x3 conv [x(8)|h(64)] -> 32, 16 oc per block ------
__global__ void k_conv1(const float* __restrict__ x, const bf16* __restrict__ h,
                        const float* __restrict__ w, const float* __restrict__ bias,
                        bf16* __restrict__ f, int t)
{
    __shared__ float wl[72*9*16];                    // 41472 B
    int tid = threadIdx.x;
    int oc0 = blockIdx.y*16, b = blockIdx.z;
    for (int i = tid; i < 72*9*16; i += 256){
        int j = i & 15, kt = i >> 4;
        wl[i] = w[(size_t)(oc0 + j)*(72*9) + kt];
    }
    __syncthreads();
    int pix = blockIdx.x*256 + tid;
    int y = pix / Ww, xc = pix % Ww;
    float acc[16];
    #pragma unroll
    for (int j=0;j<16;++j) acc[j] = bias[oc0+j];
    const float* xb = x + ((size_t)(b*Sn + t)*Cin)*HW;
    const bf16*  hb = h + (size_t)b*Chn*HW;
    for (int ic=0; ic<72; ++ic){
        float tv[9];
        #pragma unroll
        for (int ky=0; ky<3; ++ky){
            int yy = y + ky - 1;
            #pragma unroll
            for (int kx=0; kx<3; ++kx){
                int xx = xc + kx - 1;
                bool ok = (yy>=0 && yy<Hh && xx>=0 && xx<Ww);
                float v = 0.f;
                if (ok) v = (ic < Cin) ? xb[(size_t)ic*HW + yy*Ww + xx]
                                       : b2f(hb[(size_t)(ic-Cin)*HW + yy*Ww + xx]);
                tv[ky*3+kx] = v;
            }
        }
        #pragma unroll
        for (int tp=0; tp<9; ++tp){
            const float4* wp4 = (const float4*)&wl[(ic*9+tp)*16];
            float tvv = tv[tp];
            #pragma unroll
            for (int q=0;q<4;++q){
                float4 wv = wp4[q];
                acc[q*4+0] += tvv*wv.x; acc[q*4+1] += tvv*wv.y;
                acc[q*4+2] += tvv*wv.z; acc[q*4+3] += tvv*wv.w;
            }
        }
    }
    #pragma unroll
    for (int j=0;j<16;++j){
        float a = acc[j];
        f[((size_t)(b*32) + oc0 + j)*HW + pix] = f2b((a >= 0.f) ? a : LEAK*a);
    }
}

// ---------------- conv2: 3x3 conv 32 -> 26, 13 oc per block ----------------
__global__ void k_conv2(const bf16* __restrict__ f, const float* __restrict__ w,
                        const float* __restrict__ bias, bf16* __restrict__ flows)
{
    __shared__ float wl[32*9*16];                    // 18432 B (13 used of 16)
    int tid = threadIdx.x;
    int oc0 = blockIdx.y*13, b = blockIdx.z;
    for (int i = tid; i < 32*9*16; i += 256){
        int j = i & 15, kt = i >> 4;
        wl[i] = (j < 13) ? w[(size_t)(oc0 + j)*288 + kt] : 0.f;
    }
    __syncthreads();
    int pix = blockIdx.x*256 + tid;
    int y = pix / Ww, xc = pix % Ww;
    float acc[13];
    #pragma unroll
    for (int j=0;j<13;++j) acc[j] = bias[oc0+j];
    const bf16* fb = f + (size_t)b*32*HW;
    for (int ic=0; ic<32; ++ic){
        float tv[9];
        #pragma unroll
        for (int ky=0; ky<3; ++ky){
            int yy = y + ky - 1;
            #pragma unroll
            for (int kx=0; kx<3; ++kx){
                int xx = xc + kx - 1;
                bool ok = (yy>=0 && yy<Hh && xx>=0 && xx<Ww);
                tv[ky*3+kx] = ok ? b2f(fb[(size_t)ic*HW + yy*Ww + xx]) : 0.f;
            }
        }
        #pragma unroll
        for (int tp=0; tp<9; ++tp){
            const float* wp = &wl[(ic*9+tp)*16];
            float tvv = tv[tp];
            #pragma unroll
            for (int j=0;j<13;++j) acc[j] += tvv*wp[j];
        }
    }
    #pragma unroll
    for (int j=0;j<13;++j)
        flows[((size_t)(b*2*Ln) + oc0 + j)*HW + pix] = f2b(acc[j]);
}

// ---------------- warp: lane=channel, HWC gathers, (pix,832) output --------
__global__ void k_warp(const bf16* __restrict__ flows, const bf16* __restrict__ hwc,
                       bf16* __restrict__ warped, int b)
{
    int tid = threadIdx.x;
    int c = tid & 63, wv = tid >> 6;
    int l = blockIdx.y;
    const bf16* hb  = hwc + (size_t)b*HW*Chn;
    const bf16* fxp = flows + ((size_t)(b*2*Ln) + 2*l)*HW;
    const bf16* fyp = fxp + HW;
    int pixb = blockIdx.x*256 + wv*64;
    for (int i=0; i<64; ++i){
        int pix = pixb + i;
        int y = pix / Ww, xc = pix % Ww;
        float ix = ((float)xc - b2f(fxp[pix])) * (96.0f/95.0f) - 0.5f;
        float iy = ((float)y  - b2f(fyp[pix])) * (96.0f/95.0f) - 0.5f;
        float x0f = floorf(ix), y0f = floorf(iy);
        float wx1 = ix - x0f,  wy1 = iy - y0f;
        float wx0 = 1.f - wx1, wy0 = 1.f - wy1;
        float vx0 = (x0f >=  0.f && x0f <= 95.f) ? 1.f : 0.f;
        float vx1 = (x0f >= -1.f && x0f <= 94.f) ? 1.f : 0.f;
        float vy0 = (y0f >=  0.f && y0f <= 95.f) ? 1.f : 0.f;
        float vy1 = (y0f >= -1.f && y0f <= 94.f) ? 1.f : 0.f;
        int xi0 = (int)fminf(fmaxf(x0f,      0.f), 95.f);
        int xi1 = (int)fminf(fmaxf(x0f+1.f,  0.f), 95.f);
        int yi0 = (int)fminf(fmaxf(y0f,      0.f), 95.f);
        int yi1 = (int)fminf(fmaxf(y0f+1.f,  0.f), 95.f);
        float w00 = wx0*wy0*vx0*vy0, w10 = wx1*wy0*vx1*vy0;
        float w01 = wx0*wy1*vx0*vy1, w11 = wx1*wy1*vx1*vy1;
        float v00 = b2f(hb[(size_t)(yi0*Ww + xi0)*Chn + c]);
        float v10 = b2f(hb[(size_t)(yi0*Ww + xi1)*Chn + c]);
        float v01 = b2f(hb[(size_t)(yi1*Ww + xi0)*Chn + c]);
        float v11 = b2f(hb[(size_t)(yi1*Ww + xi1)*Chn + c]);
        warped[(size_t)pix*LCh + l*Chn + c] =
            f2b(v00*w00 + v10*w10 + v01*w01 + v11*w11);
    }
}

// ---------------- h2h: MFMA GEMM C[192,9216] = W[192,832] x V[832,9216] ----
// warped stored (pix, 832) = B^T (N,K); Wb stored (oc, 832) = A (M,K).
// Fragment mapping (guide §3, m89-verified): lane&15 <-> M/N index,
// (lane>>4)*8+reg <-> K; D: col=lane&15, row=(lane>>4)*4+reg.
__global__ void k_h2h(const bf16* __restrict__ warped, const bf16* __restrict__ Wb,
                      const float* __restrict__ rb, bf16* __restrict__ h2h, int b)
{
    int tid = threadIdx.x;
    int wid = tid >> 6, lane = tid & 63;
    int col = blockIdx.x*16 + (lane & 15);           // pixel
    int koff = (lane >> 4)*8;
    const short8v* bp = (const short8v*)(warped + (size_t)col*LCh + koff);
    int r0 = (wid + 0)*16 + (lane & 15);
    int r1 = (wid + 4)*16 + (lane & 15);
    int r2 = (wid + 8)*16 + (lane & 15);
    const short8v* a0 = (const short8v*)(Wb + (size_t)r0*LCh + koff);
    const short8v* a1 = (const short8v*)(Wb + (size_t)r1*LCh + koff);
    const short8v* a2 = (const short8v*)(Wb + (size_t)r2*LCh + koff);
    f32x4 acc0 = {0,0,0,0}, acc1 = {0,0,0,0}, acc2 = {0,0,0,0};
    #pragma unroll 2
    for (int kk=0; kk<26; ++kk){                     // K step = 32 bf16 = 4 short8v
        short8v bv = bp[kk*4];
        acc0 = __builtin_amdgcn_mfma_f32_16x16x32_bf16(a0[kk*4], bv, acc0, 0,0,0);
        acc1 = __builtin_amdgcn_mfma_f32_16x16x32_bf16(a1[kk*4], bv, acc1, 0,0,0);
        acc2 = __builtin_amdgcn_mfma_f32_16x16x32_bf16(a2[kk*4], bv, acc2, 0,0,0);
    }
    #pragma unroll
    for (int s=0; s<3; ++s){
        f32x4 a = (s==0) ? acc0 : ((s==1) ? acc1 : acc2);
        int rowb = (wid + 4*s)*16 + (lane >> 4)*4;
        #pragma unroll
        for (int r=0; r<4; ++r){
            float v = a[r] + rb[rowb + r];
            h2h[((size_t)(b*OC3) + rowb + r)*HW + col] = f2b(v);
        }
    }
}

// ---------------- gates: GRU update ---------------------------------------
__global__ void k_gates(const bf16* __restrict__ i2h, const bf16* __restrict__ h2h,
                        bf16* __restrict__ h, float* __restrict__ out, int t)
{
    int pix = blockIdx.x*256 + threadIdx.x;
    int cc = blockIdx.y, b = blockIdx.z;
    size_t base = (size_t)b*OC3*HW + pix;
    float i1 = b2f(i2h[base + (size_t)cc*HW]);
    float i2v= b2f(i2h[base + (size_t)(cc+ 64)*HW]);
    float i3 = b2f(i2h[base + (size_t)(cc+128)*HW]);
    float h1 = b2f(h2h[base + (size_t)cc*HW]);
    float h2v= b2f(h2h[base + (size_t)(cc+ 64)*HW]);
    float h3 = b2f(h2h[base + (size_t)(cc+128)*HW]);
    size_t hidx = ((size_t)b*Chn + cc)*HW + pix;
    float hv = b2f(h[hidx]);
    float r = 1.f/(1.f + expf(-(i1 + h1)));
    float u = 1.f/(1.f + expf(-(i2v + h2v)));
    float mp = i3 + r*h3;
    float m = (mp >= 0.f) ? mp : LEAK*mp;
    float nh = u*hv + (1.f - u)*m;
    h[hidx] = f2b(nh);
    out[(((size_t)(b*Sn+t)*Chn) + cc)*HW + pix] = nh;
}

__global__ void k_last(const bf16* __restrict__ h, float* __restrict__ out)
{
    int i = blockIdx.x*256 + threadIdx.x;
    if (i < Bn*Chn*HW) out[(size_t)Bn*Sn*Chn*HW + i] = b2f(h[i]);
}

extern "C" void kernel_launch(void* const* d_in, const int* in_sizes, int n_in,
                              void* d_out, int out_size, void* d_ws, size_t ws_size,
                              hipStream_t stream) {
    const float* inputs = (const float*)d_in[0];
    const float* states = (const float*)d_in[1];
    const float* fw1    = (const float*)d_in[2];
    const float* fb1    = (const float*)d_in[3];
    const float* fw2    = (const float*)d_in[4];
    const float* fb2    = (const float*)d_in[5];
    const float* i2h_w  = (const float*)d_in[6];
    const float* i2h_b  = (const float*)d_in[7];
    const float* ret_w  = (const float*)d_in[8];
    const float* ret_b  = (const float*)d_in[9];
    float* out = (float*)d_out;

    // ws layout (bytes), total 55,320,576 (< 59.3 MB proven safe in R1)
    char* ws = (char*)d_ws;
    bf16* h_chw   = (bf16*)(ws);                     //  4,718,592  (B,64,HW)
    bf16* h_hwc   = (bf16*)(ws +  4718592);          //  4,718,592  (B,HW,64)
    bf16* i2h_ws  = (bf16*)(ws +  9437184);          // 14,155,776  (B,192,HW)
    bf16* h2h_ws  = (bf16*)(ws + 23592960);          // 14,155,776  (B,192,HW)
    bf16* flows_ws= (bf16*)(ws + 37748736);          //  1,916,928  (B,26,HW)
    bf16* Wb      = (bf16*)(ws + 39665664);          //    319,488  (192,832)
    bf16* warped  = (bf16*)(ws + 39985152);          // 15,335,424  (HW,832) one batch
    bf16* f_ws    = warped;                          //  2,359,296  alias (dead when warp runs)

    k_wcvt<<<dim3((OC3*LCh+255)/256), 256, 0, stream>>>(ret_w, Wb, OC3*LCh);
    k_init<<<dim3((Bn*Chn*HW+255)/256), 256, 0, stream>>>(states, h_chw);
    k_tr  <<<dim3(144, Bn), 256, 0, stream>>>(h_chw, h_hwc);

    for (int t = 0; t < Sn; ++t) {
        k_i2h  <<<dim3(36, 12, Bn), 256, 0, stream>>>(inputs, i2h_w, i2h_b, i2h_ws, t);
        k_conv1<<<dim3(36,  2, Bn), 256, 0, stream>>>(inputs, h_chw, fw1, fb1, f_ws, t);
        k_conv2<<<dim3(36,  2, Bn), 256, 0, stream>>>(f_ws, fw2, fb2, flows_ws);
        for (int b = 0; b < Bn; ++b) {
            k_warp<<<dim3(36, Ln), 256, 0, stream>>>(flows_ws, h_hwc, warped, b);
            k_h2h <<<dim3(576),    256, 0, stream>>>(warped, Wb, ret_b, h2h_ws, b);
        }
        k_gates<<<dim3(36, Chn, Bn), 256, 0, stream>>>(i2h_ws, h2h_ws, h_chw, out, t);
        k_tr   <<<dim3(144, Bn), 256, 0, stream>>>(h_chw, h_hwc);
    }
    k_last<<<dim3((Bn*Chn*HW+255)/256), 256, 0, stream>>>(h_chw, out);
}

// Round 4
// 1659.984 us; speedup vs baseline: 3.4424x; 1.8219x over previous
//
#include <hip/hip_runtime.h>
#include <hip/hip_bf16.h>
#include <math.h>

#define Bn 4
#define Sn 6
#define Cin 8
#define Hh 96
#define Ww 96
#define HW (Hh*Ww)          // 9216
#define Chn 64
#define Ln 13
#define LCh (Ln*Chn)        // 832
#define OC3 (3*Chn)         // 192
#define LEAK 0.2f

typedef __hip_bfloat16 bf16;
typedef __attribute__((ext_vector_type(8))) short short8v;  // 8 bf16 (4 VGPRs)
typedef __attribute__((ext_vector_type(4))) short short4v;  // 4 bf16 (8B)
typedef __attribute__((ext_vector_type(4))) float f32x4;

__device__ __forceinline__ float b2f(bf16 v){ return __bfloat162float(v); }
__device__ __forceinline__ bf16  f2b(float v){ return __float2bfloat16(v); }
__device__ __forceinline__ short bbits(bf16 v){ union{bf16 b; short s;} u; u.b=v; return u.s; }

// ============ one-time weight packing ============
// W1b: (32, 672) k = tap*72+ic, pad 648..671 = 0   (fw1: (32,72,3,3))
__global__ void k_prep_w1(const float* __restrict__ w, bf16* __restrict__ o){
    int i = blockIdx.x*256 + threadIdx.x;
    if (i >= 32*672) return;
    int oc = i/672, k = i%672;
    float v = 0.f;
    if (k < 648){ int tap = k/72, ic = k%72; v = w[(size_t)oc*648 + ic*9 + tap]; }
    o[i] = f2b(v);
}
// W2b: (32, 288) k = tap*32+ic, oc 26..31 = 0      (fw2: (26,32,3,3))
__global__ void k_prep_w2(const float* __restrict__ w, bf16* __restrict__ o){
    int i = blockIdx.x*256 + threadIdx.x;
    if (i >= 32*288) return;
    int oc = i/288, k = i%288;
    float v = 0.f;
    if (oc < 26){ int tap = k/32, ic = k%32; v = w[(size_t)oc*288 + ic*9 + tap]; }
    o[i] = f2b(v);
}
// Wi: (192, 96) k = tap*8+ic, pad 72..95 = 0        (i2h_w: (192,8,3,3))
__global__ void k_prep_wi(const float* __restrict__ w, bf16* __restrict__ o){
    int i = blockIdx.x*256 + threadIdx.x;
    if (i >= 192*96) return;
    int oc = i/96, k = i%96;
    float v = 0.f;
    if (k < 72){ int tap = k/8, ic = k%8; v = w[(size_t)oc*72 + ic*9 + tap]; }
    o[i] = f2b(v);
}
// Wb: (192, 832) straight cvt                       (ret_w)
__global__ void k_prep_wb(const float* __restrict__ w, bf16* __restrict__ o){
    int i = blockIdx.x*256 + threadIdx.x;
    if (i < OC3*LCh) o[i] = f2b(w[i]);
}

__global__ void k_init(const float* __restrict__ s, bf16* __restrict__ h){
    int i = blockIdx.x*256 + threadIdx.x;
    if (i < Bn*Chn*HW) h[i] = f2b(s[i]);
}

// ============ pack xh (B, HW, 72) = [x_t | h] bf16, LDS transpose ============
__global__ void k_pack(const float* __restrict__ x, const bf16* __restrict__ h,
                       bf16* __restrict__ xh, int t)
{
    __shared__ unsigned short th[64][65];
    __shared__ unsigned short tx[8][64];
    int b = blockIdx.y, pix0 = blockIdx.x*64, tid = threadIdx.x;
    const unsigned short* hs = (const unsigned short*)h;
    #pragma unroll
    for (int it=0; it<18; ++it){
        int idx = it*256 + tid;
        if (idx < 4096){
            int c = idx>>6, p = idx&63;
            th[c][p] = hs[((size_t)b*Chn + c)*HW + pix0 + p];
        } else {
            int j = idx - 4096;          // 0..511
            int ic = j>>6, p = j&63;
            tx[ic][p] = (unsigned short)bbits(f2b(x[((size_t)(b*Sn+t)*Cin + ic)*HW + pix0 + p]));
        }
    }
    __syncthreads();
    for (int j = tid; j < 64*18; j += 256){
        int p = j/18, cg = j%18;
        short4v v;
        #pragma unroll
        for (int q=0;q<4;++q){
            int ch = cg*4 + q;
            v[q] = (short)((ch < 8) ? tx[ch][p] : th[ch-8][p]);
        }
        *(short4v*)&xh[((size_t)b*HW + pix0 + p)*72 + cg*4] = v;
    }
}

// ============ i2h: implicit-GEMM 3x3 conv 8->192 via MFMA ============
__global__ __launch_bounds__(384) void k_i2h(const bf16* __restrict__ xh,
        const bf16* __restrict__ Wi, const float* __restrict__ ib,
        bf16* __restrict__ out)
{
    __shared__ bf16 tile[3*98*8];                    // 4704 B
    int y = blockIdx.x, b = blockIdx.y, tid = threadIdx.x;
    const bf16* xb = xh + (size_t)b*HW*72;
    for (int s = tid; s < 294; s += 384){
        int r = s/98, px = s%98 - 1, yy = y + r - 1;
        float4* dst = (float4*)&tile[s*8];
        if (yy>=0 && yy<Hh && px>=0 && px<Ww)
            *dst = *(const float4*)(xb + ((size_t)yy*Ww + px)*72);
        else { float4 z{0,0,0,0}; *dst = z; }
    }
    __syncthreads();
    int wv = tid>>6, lane = tid&63, x0 = wv*16, n = lane&15, kg = lane>>4;
    f32x4 acc[12];
    #pragma unroll
    for (int m=0;m<12;++m) acc[m] = f32x4{0,0,0,0};
    #pragma unroll
    for (int kk=0; kk<3; ++kk){
        int g = kk*4 + kg;                           // 0..11; valid taps 0..8
        int tap = (g > 8) ? 8 : g;                   // A is zero for g>8
        int dy = tap/3, dx = tap%3;
        short8v bv = *(const short8v*)&tile[((dy*98) + (x0+n) + dx)*8];
        #pragma unroll
        for (int m=0;m<12;++m){
            short8v av = *(const short8v*)(Wi + (size_t)(m*16 + n)*96 + g*8);
            acc[m] = __builtin_amdgcn_mfma_f32_16x16x32_bf16(av, bv, acc[m], 0,0,0);
        }
    }
    int pix = y*Ww + x0 + n;
    #pragma unroll
    for (int m=0;m<12;++m){
        #pragma unroll
        for (int r=0;r<4;++r){
            int oc = m*16 + kg*4 + r;
            out[((size_t)(b*OC3)+oc)*HW + pix] = f2b(acc[m][r] + ib[oc]);
        }
    }
}

// ============ conv1: implicit-GEMM 3x3 conv 72->32 + LeakyReLU, HWC out =====
__global__ __launch_bounds__(384) void k_conv1(const bf16* __restrict__ xh,
        const bf16* __restrict__ W1b, const float* __restrict__ fb1,
        bf16* __restrict__ f_hwc)
{
    __shared__ bf16 tile[3*98*72];                   // 42336 B
    int y = blockIdx.x, b = blockIdx.y, tid = threadIdx.x;
    const bf16* xb = xh + (size_t)b*HW*72;
    for (int s = tid; s < 294; s += 384){
        int r = s/98, px = s%98 - 1, yy = y + r - 1;
        float4* dst = (float4*)&tile[s*72];
        if (yy>=0 && yy<Hh && px>=0 && px<Ww){
            const float4* src = (const float4*)(xb + ((size_t)yy*Ww + px)*72);
            #pragma unroll
            for (int q=0;q<9;++q) dst[q] = src[q];
        } else {
            float4 z{0,0,0,0};
            #pragma unroll
            for (int q=0;q<9;++q) dst[q] = z;
        }
    }
    __syncthreads();
    int wv = tid>>6, lane = tid&63, x0 = wv*16, n = lane&15, kg = lane>>4;
    f32x4 acc0{0,0,0,0}, acc1{0,0,0,0};
    #pragma unroll
    for (int kk=0; kk<21; ++kk){
        int g = kk*4 + kg;                           // 0..83; valid 0..80
        int gc = (g > 80) ? 80 : g;
        int tap = gc/9, ch0 = (gc%9)*8;
        int dy = tap/3, dx = tap%3;
        short8v bv = *(const short8v*)&tile[(((dy*98) + (x0+n) + dx))*72 + ch0];
        short8v a0 = *(const short8v*)(W1b + (size_t)n*672 + g*8);
        short8v a1 = *(const short8v*)(W1b + (size_t)(16+n)*672 + g*8);
        acc0 = __builtin_amdgcn_mfma_f32_16x16x32_bf16(a0, bv, acc0, 0,0,0);
        acc1 = __builtin_amdgcn_mfma_f32_16x16x32_bf16(a1, bv, acc1, 0,0,0);
    }
    size_t prow = (size_t)b*HW + y*Ww + x0 + n;
    #pragma unroll
    for (int mt=0; mt<2; ++mt){
        f32x4 a = mt ? acc1 : acc0;
        short4v sv;
        #pragma unroll
        for (int r=0;r<4;++r){
            int oc = mt*16 + kg*4 + r;
            float v = a[r] + fb1[oc];
            sv[r] = bbits(f2b((v >= 0.f) ? v : LEAK*v));
        }
        *(short4v*)&f_hwc[prow*32 + mt*16 + kg*4] = sv;
    }
}

// ============ conv2: implicit-GEMM 3x3 conv 32->26, CHW flows out ============
__global__ __launch_bounds__(384) void k_conv2(const bf16* __restrict__ f_hwc,
        const bf16* __restrict__ W2b, const float* __restrict__ fb2,
        bf16* __restrict__ flows)
{
    __shared__ bf16 tile[3*98*32];                   // 18816 B
    int y = blockIdx.x, b = blockIdx.y, tid = threadIdx.x;
    const bf16* fb = f_hwc + (size_t)b*HW*32;
    for (int s = tid; s < 294; s += 384){
        int r = s/98, px = s%98 - 1, yy = y + r - 1;
        float4* dst = (float4*)&tile[s*32];
        if (yy>=0 && yy<Hh && px>=0 && px<Ww){
            const float4* src = (const float4*)(fb + ((size_t)yy*Ww + px)*32);
            #pragma unroll
            for (int q=0;q<4;++q) dst[q] = src[q];
        } else {
            float4 z{0,0,0,0};
            #pragma unroll
            for (int q=0;q<4;++q) dst[q] = z;
        }
    }
    __syncthreads();
    int wv = tid>>6, lane = tid&63, x0 = wv*16, n = lane&15, kg = lane>>4;
    f32x4 acc0{0,0,0,0}, acc1{0,0,0,0};
    #pragma unroll
    for (int kk=0; kk<9; ++kk){
        int g = kk*4 + kg;                           // 0..35, all valid
        int tap = g>>2, ch0 = (g&3)*8;
        int dy = tap/3, dx = tap%3;
        short8v bv = *(const short8v*)&tile[(((dy*98) + (x0+n) + dx))*32 + ch0];
        short8v a0 = *(const short8v*)(W2b + (size_t)n*288 + g*8);
        short8v a1 = *(const short8v*)(W2b + (size_t)(16+n)*288 + g*8);
        acc0 = __builtin_amdgcn_mfma_f32_16x16x32_bf16(a0, bv, acc0, 0,0,0);
        acc1 = __builtin_amdgcn_mfma_f32_16x16x32_bf16(a1, bv, acc1, 0,0,0);
    }
    int pix = y*Ww + x0 + n;
    #pragma unroll
    for (int mt=0; mt<2; ++mt){
        f32x4 a = mt ? acc1 : acc0;
        #pragma unroll
        for (int r=0;r<4;++r){
            int oc = mt*16 + kg*4 + r;
            if (oc < 26)
                flows[((size_t)(b*2*Ln)+oc)*HW + pix] = f2b(a[r] + fb2[oc]);
        }
    }
}

// ============ warp: lane=channel, xh gathers (stride 72), (pix,832) out =====
__global__ void k_warp(const bf16* __restrict__ flows, const bf16* __restrict__ xh,
                       bf16* __restrict__ warped, int b)
{
    int tid = threadIdx.x;
    int c = tid & 63, wv = tid >> 6;
    int l = blockIdx.y;
    const bf16* hb  = xh + (size_t)b*HW*72 + 8;      // h channels at slots 8..71
    const bf16* fxp = flows + ((size_t)(b*2*Ln) + 2*l)*HW;
    const bf16* fyp = fxp + HW;
    int pixb = blockIdx.x*64 + wv*16;
    for (int i=0; i<16; ++i){
        int pix = pixb + i;
        int y = pix / Ww, xc = pix % Ww;
        float ix = ((float)xc - b2f(fxp[pix])) * (96.0f/95.0f) - 0.5f;
        float iy = ((float)y  - b2f(fyp[pix])) * (96.0f/95.0f) - 0.5f;
        float x0f = floorf(ix), y0f = floorf(iy);
        float wx1 = ix - x0f,  wy1 = iy - y0f;
        float wx0 = 1.f - wx1, wy0 = 1.f - wy1;
        float vx0 = (x0f >=  0.f && x0f <= 95.f) ? 1.f : 0.f;
        float vx1 = (x0f >= -1.f && x0f <= 94.f) ? 1.f : 0.f;
        float vy0 = (y0f >=  0.f && y0f <= 95.f) ? 1.f : 0.f;
        float vy1 = (y0f >= -1.f && y0f <= 94.f) ? 1.f : 0.f;
        int xi0 = (int)fminf(fmaxf(x0f,      0.f), 95.f);
        int xi1 = (int)fminf(fmaxf(x0f+1.f,  0.f), 95.f);
        int yi0 = (int)fminf(fmaxf(y0f,      0.f), 95.f);
        int yi1 = (int)fminf(fmaxf(y0f+1.f,  0.f), 95.f);
        float w00 = wx0*wy0*vx0*vy0, w10 = wx1*wy0*vx1*vy0;
        float w01 = wx0*wy1*vx0*vy1, w11 = wx1*wy1*vx1*vy1;
        float v00 = b2f(hb[(size_t)(yi0*Ww + xi0)*72 + c]);
        float v10 = b2f(hb[(size_t)(yi0*Ww + xi1)*72 + c]);
        float v01 = b2f(hb[(size_t)(yi1*Ww + xi0)*72 + c]);
        float v11 = b2f(hb[(size_t)(yi1*Ww + xi1)*72 + c]);
        warped[(size_t)pix*LCh + l*Chn + c] =
            f2b(v00*w00 + v10*w10 + v01*w01 + v11*w11);
    }
}

// ============ h2h: MFMA GEMM C[192,9216] = W[192,832] x V[832,9216] ========
__global__ void k_h2h(const bf16* __restrict__ warped, const bf16* __restrict__ Wb,
                      const float* __restrict__ rb, bf16* __restrict__ h2h, int b)
{
    int tid = threadIdx.x;
    int wid = tid >> 6, lane = tid & 63;
    int col = blockIdx.x*16 + (lane & 15);           // pixel
    int koff = (lane >> 4)*8;
    const short8v* bp = (const short8v*)(warped + (size_t)col*LCh + koff);
    int r0 = (wid + 0)*16 + (lane & 15);
    int r1 = (wid + 4)*16 + (lane & 15);
    int r2 = (wid + 8)*16 + (lane & 15);
    const short8v* a0 = (const short8v*)(Wb + (size_t)r0*LCh + koff);
    const short8v* a1 = (const short8v*)(Wb + (size_t)r1*LCh + koff);
    const short8v* a2 = (const short8v*)(Wb + (size_t)r2*LCh + koff);
    f32x4 acc0 = {0,0,0,0}, acc1 = {0,0,0,0}, acc2 = {0,0,0,0};
    #pragma unroll 2
    for (int kk=0; kk<26; ++kk){
        short8v bv = bp[kk*4];
        acc0 = __builtin_amdgcn_mfma_f32_16x16x32_bf16(a0[kk*4], bv, acc0, 0,0,0);
        acc1 = __builtin_amdgcn_mfma_f32_16x16x32_bf16(a1[kk*4], bv, acc1, 0,0,0);
        acc2 = __builtin_amdgcn_mfma_f32_16x16x32_bf16(a2[kk*4], bv, acc2, 0,0,0);
    }
    #pragma unroll
    for (int s=0; s<3; ++s){
        f32x4 a = (s==0) ? acc0 : ((s==1) ? acc1 : acc2);
        int rowb = (wid + 4*s)*16 + (lane >> 4)*4;
        #pragma unroll
        for (int r=0; r<4; ++r){
            float v = a[r] + rb[rowb + r];
            h2h[((size_t)(b*OC3) + rowb + r)*HW + col] = f2b(v);
        }
    }
}

// ============ gates ============
__global__ void k_gates(const bf16* __restrict__ i2h, const bf16* __restrict__ h2h,
                        bf16* __restrict__ h, float* __restrict__ out, int t)
{
    int pix = blockIdx.x*256 + threadIdx.x;
    int cc = blockIdx.y, b = blockIdx.z;
    size_t base = (size_t)b*OC3*HW + pix;
    float i1 = b2f(i2h[base + (size_t)cc*HW]);
    float i2v= b2f(i2h[base + (size_t)(cc+ 64)*HW]);
    float i3 = b2f(i2h[base + (size_t)(cc+128)*HW]);
    float h1 = b2f(h2h[base + (size_t)cc*HW]);
    float h2v= b2f(h2h[base + (size_t)(cc+ 64)*HW]);
    float h3 = b2f(h2h[base + (size_t)(cc+128)*HW]);
    size_t hidx = ((size_t)b*Chn + cc)*HW + pix;
    float hv = b2f(h[hidx]);
    float r = 1.f/(1.f + expf(-(i1 + h1)));
    float u = 1.f/(1.f + expf(-(i2v + h2v)));
    float mp = i3 + r*h3;
    float m = (mp >= 0.f) ? mp : LEAK*mp;
    float nh = u*hv + (1.f - u)*m;
    h[hidx] = f2b(nh);
    out[(((size_t)(b*Sn+t)*Chn) + cc)*HW + pix] = nh;
}

__global__ void k_last(const bf16* __restrict__ h, float* __restrict__ out)
{
    int i = blockIdx.x*256 + threadIdx.x;
    if (i < Bn*Chn*HW) out[(size_t)Bn*Sn*Chn*HW + i] = b2f(h[i]);
}

extern "C" void kernel_launch(void* const* d_in, const int* in_sizes, int n_in,
                              void* d_out, int out_size, void* d_ws, size_t ws_size,
                              hipStream_t stream) {
    const float* inputs = (const float*)d_in[0];
    const float* states = (const float*)d_in[1];
    const float* fw1    = (const float*)d_in[2];
    const float* fb1    = (const float*)d_in[3];
    const float* fw2    = (const float*)d_in[4];
    const float* fb2    = (const float*)d_in[5];
    const float* i2h_w  = (const float*)d_in[6];
    const float* i2h_b  = (const float*)d_in[7];
    const float* ret_w  = (const float*)d_in[8];
    const float* ret_b  = (const float*)d_in[9];
    float* out = (float*)d_out;

    // ws layout (bytes), total 56,008,704 (< 59.3 MB proven safe)
    char* ws = (char*)d_ws;
    bf16* h_chw   = (bf16*)(ws);                     //  4,718,592  (B,64,HW)
    bf16* xh      = (bf16*)(ws +  4718592);          //  5,308,416  (B,HW,72)
    bf16* i2h_ws  = (bf16*)(ws + 10027008);          // 14,155,776  (B,192,HW)
    bf16* h2h_ws  = (bf16*)(ws + 24182784);          // 14,155,776  (B,192,HW)
    bf16* flows_ws= (bf16*)(ws + 38338560);          //  1,916,928  (B,26,HW)
    bf16* W1b     = (bf16*)(ws + 40255488);          //     43,008  (32,672)
    bf16* W2b     = (bf16*)(ws + 40298496);          //     18,432  (32,288)
    bf16* Wi      = (bf16*)(ws + 40316928);          //     36,864  (192,96)
    bf16* Wb      = (bf16*)(ws + 40353792);          //    319,488  (192,832)
    bf16* warped  = (bf16*)(ws + 40673280);          // 15,335,424  (HW,832) one batch
    bf16* f_hwc   = warped;                          //  2,359,296  alias (dead when warp runs)

    k_prep_w1<<<dim3((32*672 +255)/256), 256, 0, stream>>>(fw1,   W1b);
    k_prep_w2<<<dim3((32*288 +255)/256), 256, 0, stream>>>(fw2,   W2b);
    k_prep_wi<<<dim3((192*96 +255)/256), 256, 0, stream>>>(i2h_w, Wi);
    k_prep_wb<<<dim3((OC3*LCh+255)/256), 256, 0, stream>>>(ret_w, Wb);
    k_init<<<dim3((Bn*Chn*HW+255)/256), 256, 0, stream>>>(states, h_chw);

    for (int t = 0; t < Sn; ++t) {
        k_pack <<<dim3(144, Bn), 256, 0, stream>>>(inputs, h_chw, xh, t);
        k_i2h  <<<dim3(96, Bn), 384, 0, stream>>>(xh, Wi, i2h_b, i2h_ws);
        k_conv1<<<dim3(96, Bn), 384, 0, stream>>>(xh, W1b, fb1, f_hwc);
        k_conv2<<<dim3(96, Bn), 384, 0, stream>>>(f_hwc, W2b, fb2, flows_ws);
        for (int b = 0; b < Bn; ++b) {
            k_warp<<<dim3(144, Ln), 256, 0, stream>>>(flows_ws, xh, warped, b);
            k_h2h <<<dim3(576),     256, 0, stream>>>(warped, Wb, ret_b, h2h_ws, b);
        }
        k_gates<<<dim3(36, Chn, Bn), 256, 0, stream>>>(i2h_ws, h2h_ws, h_chw, out, t);
    }
    k_last<<<dim3((Bn*Chn*HW+255)/256), 256, 0, stream>>>(h_chw, out);
}

// Round 5
// 925.713 us; speedup vs baseline: 6.1728x; 1.7932x over previous
//
#include <hip/hip_runtime.h>
#include <hip/hip_bf16.h>
#include <math.h>

#define Bn 4
#define Sn 6
#define Cin 8
#define Hh 96
#define Ww 96
#define HW (Hh*Ww)          // 9216
#define Chn 64
#define Ln 13
#define LCh (Ln*Chn)        // 832
#define OC3 (3*Chn)         // 192
#define LEAK 0.2f

typedef __hip_bfloat16 bf16;
typedef __attribute__((ext_vector_type(8))) short short8v;  // 8 bf16 (4 VGPRs)
typedef __attribute__((ext_vector_type(4))) short short4v;  // 4 bf16 (8B)
typedef __attribute__((ext_vector_type(4))) float f32x4;

__device__ __forceinline__ float b2f(bf16 v){ return __bfloat162float(v); }
__device__ __forceinline__ bf16  f2b(float v){ return __float2bfloat16(v); }
__device__ __forceinline__ unsigned short bbits(bf16 v){ union{bf16 b; unsigned short s;} u; u.b=v; return u.s; }

// ============ merged one-time prep: weight packs + h init ============
// ranges: [0,21504) W1b | [21504,30720) W2b | [30720,49152) Wi
//         [49152,208896) Wb | [208896,2568192) h init
__global__ void k_prep(const float* __restrict__ fw1, const float* __restrict__ fw2,
                       const float* __restrict__ wi,  const float* __restrict__ rw,
                       const float* __restrict__ states,
                       bf16* __restrict__ W1b, bf16* __restrict__ W2b,
                       bf16* __restrict__ Wi,  bf16* __restrict__ Wb,
                       bf16* __restrict__ h_chw)
{
    int i = blockIdx.x*256 + threadIdx.x;
    if (i < 21504){                                   // W1b (32,672) k=tap*72+ic
        int oc = i/672, k = i%672; float v = 0.f;
        if (k < 648){ int tap = k/72, ic = k%72; v = fw1[(size_t)oc*648 + ic*9 + tap]; }
        W1b[i] = f2b(v);
    } else if (i < 30720){                            // W2b (32,288) k=tap*32+ic
        int j = i-21504; int oc = j/288, k = j%288; float v = 0.f;
        if (oc < 26){ int tap = k/32, ic = k%32; v = fw2[(size_t)oc*288 + ic*9 + tap]; }
        W2b[j] = f2b(v);
    } else if (i < 49152){                            // Wi (192,96) k=tap*8+ic
        int j = i-30720; int oc = j/96, k = j%96; float v = 0.f;
        if (k < 72){ int tap = k/8, ic = k%8; v = wi[(size_t)oc*72 + ic*9 + tap]; }
        Wi[j] = f2b(v);
    } else if (i < 208896){                           // Wb (192,832)
        int j = i-49152; Wb[j] = f2b(rw[j]);
    } else if (i < 2568192){                          // h init
        int j = i-208896; h_chw[j] = f2b(states[j]);
    }
}

// ============ pack x (B,S,C,HW) f32 -> x_hwc (B*S, HW, 8) bf16, once ========
__global__ void k_packx(const float* __restrict__ x, bf16* __restrict__ x_hwc)
{
    __shared__ unsigned short tx[8][68];
    int bs = blockIdx.y, pix0 = blockIdx.x*64, tid = threadIdx.x;
    #pragma unroll
    for (int it=0; it<2; ++it){
        int idx = it*256 + tid, ic = idx>>6, p = idx&63;
        tx[ic][p] = bbits(f2b(x[((size_t)bs*Cin + ic)*HW + pix0 + p]));
    }
    __syncthreads();
    unsigned short* dst = (unsigned short*)x_hwc;
    #pragma unroll
    for (int it=0; it<2; ++it){
        int j = it*256 + tid, p = j>>3, c = j&7;
        dst[((size_t)bs*HW + pix0 + p)*8 + c] = tx[c][p];
    }
}

// ============ pack h: h_chw (B,64,HW) -> h_hwc (B,HW,64), per step ==========
__global__ void k_packh(const bf16* __restrict__ chw, bf16* __restrict__ hwc)
{
    __shared__ unsigned short t[64][65];
    int b = blockIdx.y, pix0 = blockIdx.x*64, tid = threadIdx.x;
    const unsigned short* src = (const unsigned short*)chw;
    unsigned short* dst = (unsigned short*)hwc;
    #pragma unroll
    for (int it=0; it<16; ++it){
        int idx = it*256 + tid, c = idx>>6, p = idx&63;
        t[c][p] = src[((size_t)b*Chn + c)*HW + pix0 + p];
    }
    __syncthreads();
    #pragma unroll
    for (int it=0; it<16; ++it){
        int idx = it*256 + tid, p = idx>>6, c = idx&63;
        dst[((size_t)b*HW + pix0 + p)*Chn + c] = t[c][p];
    }
}

// ============ i2h: implicit-GEMM 3x3 conv 8->192 via MFMA ============
__global__ __launch_bounds__(384) void k_i2h(const bf16* __restrict__ x_hwc,
        const bf16* __restrict__ Wi, const float* __restrict__ ib,
        bf16* __restrict__ out, int t)
{
    __shared__ bf16 tile[3*98*8];                    // 4704 B
    int y = blockIdx.x, b = blockIdx.y, tid = threadIdx.x;
    const bf16* xb = x_hwc + (size_t)(b*Sn + t)*HW*8;
    for (int s = tid; s < 294; s += 384){
        int r = s/98, px = s%98 - 1, yy = y + r - 1;
        float4* dst = (float4*)&tile[s*8];
        if (yy>=0 && yy<Hh && px>=0 && px<Ww)
            *dst = *(const float4*)(xb + ((size_t)yy*Ww + px)*8);
        else { float4 z{0,0,0,0}; *dst = z; }
    }
    __syncthreads();
    int wv = tid>>6, lane = tid&63, x0 = wv*16, n = lane&15, kg = lane>>4;
    f32x4 acc[12];
    #pragma unroll
    for (int m=0;m<12;++m) acc[m] = f32x4{0,0,0,0};
    #pragma unroll
    for (int kk=0; kk<3; ++kk){
        int g = kk*4 + kg;                           // 0..11; valid taps 0..8
        int tap = (g > 8) ? 8 : g;                   // A is zero for g>8
        int dy = tap/3, dx = tap%3;
        short8v bv = *(const short8v*)&tile[((dy*98) + (x0+n) + dx)*8];
        #pragma unroll
        for (int m=0;m<12;++m){
            short8v av = *(const short8v*)(Wi + (size_t)(m*16 + n)*96 + g*8);
            acc[m] = __builtin_amdgcn_mfma_f32_16x16x32_bf16(av, bv, acc[m], 0,0,0);
        }
    }
    int pix = y*Ww + x0 + n;
    #pragma unroll
    for (int m=0;m<12;++m){
        #pragma unroll
        for (int r=0;r<4;++r){
            int oc = m*16 + kg*4 + r;
            out[((size_t)(b*OC3)+oc)*HW + pix] = f2b(acc[m][r] + ib[oc]);
        }
    }
}

// ============ conv1: implicit-GEMM 3x3 [x(8)|h(64)] -> 32 + LeakyReLU =======
__global__ __launch_bounds__(384) void k_conv1(const bf16* __restrict__ x_hwc,
        const bf16* __restrict__ h_hwc,
        const bf16* __restrict__ W1b, const float* __restrict__ fb1,
        bf16* __restrict__ f_hwc, int t)
{
    __shared__ bf16 tile[3*98*72];                   // 42336 B
    int y = blockIdx.x, b = blockIdx.y, tid = threadIdx.x;
    const bf16* xb = x_hwc + (size_t)(b*Sn + t)*HW*8;
    const bf16* hb = h_hwc + (size_t)b*HW*64;
    for (int s = tid; s < 294; s += 384){
        int r = s/98, px = s%98 - 1, yy = y + r - 1;
        float4* dst = (float4*)&tile[s*72];
        if (yy>=0 && yy<Hh && px>=0 && px<Ww){
            size_t gp = (size_t)yy*Ww + px;
            dst[0] = *(const float4*)(xb + gp*8);
            const float4* hsrc = (const float4*)(hb + gp*64);
            #pragma unroll
            for (int q=0;q<8;++q) dst[1+q] = hsrc[q];
        } else {
            float4 z{0,0,0,0};
            #pragma unroll
            for (int q=0;q<9;++q) dst[q] = z;
        }
    }
    __syncthreads();
    int wv = tid>>6, lane = tid&63, x0 = wv*16, n = lane&15, kg = lane>>4;
    f32x4 acc0{0,0,0,0}, acc1{0,0,0,0};
    #pragma unroll
    for (int kk=0; kk<21; ++kk){
        int g = kk*4 + kg;                           // 0..83; valid 0..80
        int gc = (g > 80) ? 80 : g;
        int tap = gc/9, ch0 = (gc%9)*8;
        int dy = tap/3, dx = tap%3;
        short8v bv = *(const short8v*)&tile[(((dy*98) + (x0+n) + dx))*72 + ch0];
        short8v a0 = *(const short8v*)(W1b + (size_t)n*672 + g*8);
        short8v a1 = *(const short8v*)(W1b + (size_t)(16+n)*672 + g*8);
        acc0 = __builtin_amdgcn_mfma_f32_16x16x32_bf16(a0, bv, acc0, 0,0,0);
        acc1 = __builtin_amdgcn_mfma_f32_16x16x32_bf16(a1, bv, acc1, 0,0,0);
    }
    size_t prow = (size_t)b*HW + y*Ww + x0 + n;
    #pragma unroll
    for (int mt=0; mt<2; ++mt){
        f32x4 a = mt ? acc1 : acc0;
        short4v sv;
        #pragma unroll
        for (int r=0;r<4;++r){
            int oc = mt*16 + kg*4 + r;
            float v = a[r] + fb1[oc];
            sv[r] = (short)bbits(f2b((v >= 0.f) ? v : LEAK*v));
        }
        *(short4v*)&f_hwc[prow*32 + mt*16 + kg*4] = sv;
    }
}

// ============ conv2: implicit-GEMM 3x3 conv 32->26, CHW flows out ============
__global__ __launch_bounds__(384) void k_conv2(const bf16* __restrict__ f_hwc,
        const bf16* __restrict__ W2b, const float* __restrict__ fb2,
        bf16* __restrict__ flows)
{
    __shared__ bf16 tile[3*98*32];                   // 18816 B
    int y = blockIdx.x, b = blockIdx.y, tid = threadIdx.x;
    const bf16* fb = f_hwc + (size_t)b*HW*32;
    for (int s = tid; s < 294; s += 384){
        int r = s/98, px = s%98 - 1, yy = y + r - 1;
        float4* dst = (float4*)&tile[s*32];
        if (yy>=0 && yy<Hh && px>=0 && px<Ww){
            const float4* src = (const float4*)(fb + ((size_t)yy*Ww + px)*32);
            #pragma unroll
            for (int q=0;q<4;++q) dst[q] = src[q];
        } else {
            float4 z{0,0,0,0};
            #pragma unroll
            for (int q=0;q<4;++q) dst[q] = z;
        }
    }
    __syncthreads();
    int wv = tid>>6, lane = tid&63, x0 = wv*16, n = lane&15, kg = lane>>4;
    f32x4 acc0{0,0,0,0}, acc1{0,0,0,0};
    #pragma unroll
    for (int kk=0; kk<9; ++kk){
        int g = kk*4 + kg;                           // 0..35, all valid
        int tap = g>>2, ch0 = (g&3)*8;
        int dy = tap/3, dx = tap%3;
        short8v bv = *(const short8v*)&tile[(((dy*98) + (x0+n) + dx))*32 + ch0];
        short8v a0 = *(const short8v*)(W2b + (size_t)n*288 + g*8);
        short8v a1 = *(const short8v*)(W2b + (size_t)(16+n)*288 + g*8);
        acc0 = __builtin_amdgcn_mfma_f32_16x16x32_bf16(a0, bv, acc0, 0,0,0);
        acc1 = __builtin_amdgcn_mfma_f32_16x16x32_bf16(a1, bv, acc1, 0,0,0);
    }
    int pix = y*Ww + x0 + n;
    #pragma unroll
    for (int mt=0; mt<2; ++mt){
        f32x4 a = mt ? acc1 : acc0;
        #pragma unroll
        for (int r=0;r<4;++r){
            int oc = mt*16 + kg*4 + r;
            if (oc < 26)
                flows[((size_t)(b*2*Ln)+oc)*HW + pix] = f2b(a[r] + fb2[oc]);
        }
    }
}

// ============ fused warp(LDS) + h2h MFMA + GRU gates ========================
// Block: 16 pixels, 256 threads. LDS holds warped[16][832] bf16, rows 1664 B,
// byte-offset XOR-swizzled with ((px&7)<<4) for conflict-free b128 reads.
__global__ __launch_bounds__(256) void k_fused(const bf16* __restrict__ flows,
        const bf16* __restrict__ h_hwc, const bf16* __restrict__ Wb,
        const float* __restrict__ rb, const bf16* __restrict__ i2h_ws,
        bf16* __restrict__ h_chw, float* __restrict__ out, int t)
{
    __shared__ bf16 wlds[16*LCh];                    // 26624 B
    char* ldsb = (char*)wlds;
    int tid = threadIdx.x, wv = tid>>6, lane = tid&63;
    int b = blockIdx.y, pix0 = blockIdx.x*16;
    const bf16* hb  = h_hwc + (size_t)b*HW*64;
    const bf16* flb = flows + (size_t)b*2*Ln*HW;

    // ---- phase 1: bilinear warp into LDS (wave wv handles px%4==wv) ----
    int c = lane;                                    // channel
    for (int pr = wv; pr < 16*Ln; pr += 4){
        int px = pr & 15, l = pr >> 4;
        int pix = pix0 + px;
        int y = pix / Ww, xc = pix % Ww;
        float ix = ((float)xc - b2f(flb[(size_t)(2*l  )*HW + pix])) * (96.0f/95.0f) - 0.5f;
        float iy = ((float)y  - b2f(flb[(size_t)(2*l+1)*HW + pix])) * (96.0f/95.0f) - 0.5f;
        float x0f = floorf(ix), y0f = floorf(iy);
        float wx1 = ix - x0f,  wy1 = iy - y0f;
        float wx0 = 1.f - wx1, wy0 = 1.f - wy1;
        float vx0 = (x0f >=  0.f && x0f <= 95.f) ? 1.f : 0.f;
        float vx1 = (x0f >= -1.f && x0f <= 94.f) ? 1.f : 0.f;
        float vy0 = (y0f >=  0.f && y0f <= 95.f) ? 1.f : 0.f;
        float vy1 = (y0f >= -1.f && y0f <= 94.f) ? 1.f : 0.f;
        int xi0 = (int)fminf(fmaxf(x0f,      0.f), 95.f);
        int xi1 = (int)fminf(fmaxf(x0f+1.f,  0.f), 95.f);
        int yi0 = (int)fminf(fmaxf(y0f,      0.f), 95.f);
        int yi1 = (int)fminf(fmaxf(y0f+1.f,  0.f), 95.f);
        float w00 = wx0*wy0*vx0*vy0, w10 = wx1*wy0*vx1*vy0;
        float w01 = wx0*wy1*vx0*vy1, w11 = wx1*wy1*vx1*vy1;
        float v = b2f(hb[(size_t)(yi0*Ww + xi0)*64 + c])*w00
                + b2f(hb[(size_t)(yi0*Ww + xi1)*64 + c])*w10
                + b2f(hb[(size_t)(yi1*Ww + xi0)*64 + c])*w01
                + b2f(hb[(size_t)(yi1*Ww + xi1)*64 + c])*w11;
        int k = l*64 + c;
        int off = px*1664 + ((k*2) ^ ((px&7)<<4));
        *(bf16*)(ldsb + off) = f2b(v);
    }
    __syncthreads();

    // ---- phase 2: GEMM C[192,16] = Wb[192,832] x warped_lds[832,16] ----
    int col = lane & 15, kg = lane >> 4;
    int r0 = (wv + 0)*16 + col;
    int r1 = (wv + 4)*16 + col;
    int r2 = (wv + 8)*16 + col;
    const short8v* a0 = (const short8v*)(Wb + (size_t)r0*LCh + kg*8);
    const short8v* a1 = (const short8v*)(Wb + (size_t)r1*LCh + kg*8);
    const short8v* a2 = (const short8v*)(Wb + (size_t)r2*LCh + kg*8);
    f32x4 acc0{0,0,0,0}, acc1{0,0,0,0}, acc2{0,0,0,0};
    int swz = (col&7)<<4;
    #pragma unroll 2
    for (int kk=0; kk<26; ++kk){
        int off = col*1664 + ((kk*64 + kg*16) ^ swz);
        short8v bv = *(const short8v*)(ldsb + off);
        acc0 = __builtin_amdgcn_mfma_f32_16x16x32_bf16(a0[kk*4], bv, acc0, 0,0,0);
        acc1 = __builtin_amdgcn_mfma_f32_16x16x32_bf16(a1[kk*4], bv, acc1, 0,0,0);
        acc2 = __builtin_amdgcn_mfma_f32_16x16x32_bf16(a2[kk*4], bv, acc2, 0,0,0);
    }

    // ---- phase 3: GRU gates from accumulators ----
    int pix = pix0 + col;
    const bf16* ib = i2h_ws + (size_t)b*OC3*HW;
    #pragma unroll
    for (int r=0; r<4; ++r){
        int cc = wv*16 + kg*4 + r;                   // 0..63
        float h1 = acc0[r] + rb[cc];
        float h2 = acc1[r] + rb[cc+64];
        float h3 = acc2[r] + rb[cc+128];
        float i1 = b2f(ib[(size_t)cc*HW + pix]);
        float i2v= b2f(ib[(size_t)(cc+ 64)*HW + pix]);
        float i3 = b2f(ib[(size_t)(cc+128)*HW + pix]);
        size_t hidx = ((size_t)b*Chn + cc)*HW + pix;
        float hv = b2f(h_chw[hidx]);
        float rg = 1.f/(1.f + expf(-(i1 + h1)));
        float u  = 1.f/(1.f + expf(-(i2v + h2)));
        float mp = i3 + rg*h3;
        float m  = (mp >= 0.f) ? mp : LEAK*mp;
        float nh = u*hv + (1.f - u)*m;
        h_chw[hidx] = f2b(nh);
        out[(((size_t)(b*Sn+t))*Chn + cc)*HW + pix] = nh;
    }
}

__global__ void k_last(const bf16* __restrict__ h, float* __restrict__ out)
{
    int i = blockIdx.x*256 + threadIdx.x;
    if (i < Bn*Chn*HW) out[(size_t)Bn*Sn*Chn*HW + i] = b2f(h[i]);
}

extern "C" void kernel_launch(void* const* d_in, const int* in_sizes, int n_in,
                              void* d_out, int out_size, void* d_ws, size_t ws_size,
                              hipStream_t stream) {
    const float* inputs = (const float*)d_in[0];
    const float* states = (const float*)d_in[1];
    const float* fw1    = (const float*)d_in[2];
    const float* fb1    = (const float*)d_in[3];
    const float* fw2    = (const float*)d_in[4];
    const float* fb2    = (const float*)d_in[5];
    const float* i2h_w  = (const float*)d_in[6];
    const float* i2h_b  = (const float*)d_in[7];
    const float* ret_w  = (const float*)d_in[8];
    const float* ret_b  = (const float*)d_in[9];
    float* out = (float*)d_out;

    // ws layout (bytes), total 31,825,920 (~31.8 MB, < 59.3 MB proven safe)
    char* ws = (char*)d_ws;
    bf16* h_chw   = (bf16*)(ws);                     //  4,718,592  (B,64,HW)
    bf16* h_hwc   = (bf16*)(ws +  4718592);          //  4,718,592  (B,HW,64)
    bf16* x_hwc   = (bf16*)(ws +  9437184);          //  3,538,944  (B*S,HW,8)
    bf16* i2h_ws  = (bf16*)(ws + 12976128);          // 14,155,776  (B,192,HW)
    bf16* f_hwc   = (bf16*)(ws + 27131904);          //  2,359,296  (B,HW,32)
    bf16* flows_ws= (bf16*)(ws + 29491200);          //  1,916,928  (B,26,HW)
    bf16* W1b     = (bf16*)(ws + 31408128);          //     43,008  (32,672)
    bf16* W2b     = (bf16*)(ws + 31451136);          //     18,432  (32,288)
    bf16* Wi      = (bf16*)(ws + 31469568);          //     36,864  (192,96)
    bf16* Wb      = (bf16*)(ws + 31506432);          //    319,488  (192,832)

    k_prep <<<dim3(10032),      256, 0, stream>>>(fw1, fw2, i2h_w, ret_w, states,
                                                  W1b, W2b, Wi, Wb, h_chw);
    k_packx<<<dim3(144, Bn*Sn), 256, 0, stream>>>(inputs, x_hwc);
    k_packh<<<dim3(144, Bn),    256, 0, stream>>>(h_chw, h_hwc);

    for (int t = 0; t < Sn; ++t) {
        k_i2h  <<<dim3(96, Bn),  384, 0, stream>>>(x_hwc, Wi, i2h_b, i2h_ws, t);
        k_conv1<<<dim3(96, Bn),  384, 0, stream>>>(x_hwc, h_hwc, W1b, fb1, f_hwc, t);
        k_conv2<<<dim3(96, Bn),  384, 0, stream>>>(f_hwc, W2b, fb2, flows_ws);
        k_fused<<<dim3(576, Bn), 256, 0, stream>>>(flows_ws, h_hwc, Wb, ret_b,
                                                   i2h_ws, h_chw, out, t);
        if (t < Sn-1)
            k_packh<<<dim3(144, Bn), 256, 0, stream>>>(h_chw, h_hwc);
    }
    k_last<<<dim3((Bn*Chn*HW+255)/256), 256, 0, stream>>>(h_chw, out);
}